// Round 10
// baseline (24.746 us; speedup 1.0000x reference)
//
#include <hip/hip_runtime.h>
#include <hip/hip_bf16.h>

#define EPS 1e-07f

#define BLOCK 1024
#define RPB   32            // rays per block (one wave-half per K-chunk)
#define NW    (BLOCK/64)    // 16 waves

// sqrt(0.5*log2(e)) ; log2(sqrt(2*pi))
#define SQRT_HALF_LOG2E 0.84932180028801904f
#define LOG2_SQRT_2PI   1.32574806473616588f

typedef float v4f __attribute__((ext_vector_type(4)));

// VALU-only rsqrt: Quake seed + 2 Newton iterations. rel err ~4e-6.
// 9 VALU ops, zero transcendental-pipe use.
__device__ __forceinline__ float nr_rsqrt(float a) {
    int i = __float_as_int(a);
    i = 0x5f3759df - (i >> 1);
    float y = __int_as_float(i);
    float h = 0.5f * a;
    y = y * fmaf(-(h * y), y, 1.5f);
    y = y * fmaf(-(h * y), y, 1.5f);
    return y;
}

// ---------------------------------------------------------------------------
// Single fused kernel (round-8 structure; ONLY change: rsq -> VALU Newton).
//  grid.x = R/RPB blocks, 1024 threads (16 waves).
//  Each block handles 32 rays over ALL K Gaussians in 2 passes of K/2:
//   phase 1: block precomputes K/2 Gaussian records into LDS (redundant
//            across blocks). Record: m00' m01' m11' (S/detS), cc, pos0, pos1
//            via cross-product identity  c0 - b^2/a = (u x (p-pos))^2 / a'.
//   phase 2: wave w, half h walks chunk c=(w<<1)|h.
//  Reduction: shfl_xor(32) + LDS tree; plain store. No atomics, no ws.
// ---------------------------------------------------------------------------
__global__ __launch_bounds__(BLOCK) void fused_splat(
        const float* __restrict__ pos_raw,
        const float* __restrict__ conc_raw,
        const float* __restrict__ scale_raw,
        const float* __restrict__ rot_raw,
        const void*  __restrict__ map_size_p,
        const float* __restrict__ p_rays,
        const float* __restrict__ u_rays,
        float* __restrict__ out,
        int K, int R)
{
    // K/2 = 2048 Gaussians per pass -> 512 groups -> 48 KB
    __shared__ float sG[512][6][4];
    __shared__ float psum[NW][RPB];

    const int tid  = threadIdx.x;
    const int lane = tid & 63;
    const int wv   = tid >> 6;          // 0..15
    const int rayl = lane & 31;         // ray within block
    const int half = lane >> 5;         // 0/1
    const int chunk = (wv << 1) | half; // 0..31

    int ray = blockIdx.x * RPB + rayl;
    if (ray >= R) ray = R - 1;          // defensive (R % RPB == 0 normally)

    // map_size may arrive as int32 or float32 single-element array.
    unsigned int msbits = *(const unsigned int*)map_size_p;
    float msf = __uint_as_float(msbits);
    const float ms = (msf >= 1e-3f && msf <= 1e9f) ? msf
                                                   : (float)(*(const int*)map_size_p);

    // Per-ray coefficients.
    float2 p2 = *(const float2*)(p_rays + 2*ray);
    float2 u2 = *(const float2*)(u_rays + 2*ray);
    const float p0 = p2.x, p1 = p2.y, u0 = u2.x, u1 = u2.y;
    const float qu0  = u0*u0, qu1 = 2.0f*u0*u1, qu2 = u1*u1;
    const float wt   =  SQRT_HALF_LOG2E * (u0*p1 - u1*p0);
    const float su1  =  SQRT_HALF_LOG2E * u1;
    const float nsu0 = -SQRT_HALF_LOG2E * u0;

    float acc = 0.0f;

    const int KH = K >> 1;              // Gaussians per pass (2048)
    const int CL = KH >> 5;             // chunk length (64)
    const int NG = CL >> 2;             // groups per chunk (16)

    for (int pass = 0; pass < 2; ++pass) {
        const int kbase = pass * KH;

        __syncthreads();                // previous pass fully consumed

        // ---- phase 1: precompute this pass's Gaussians into LDS ----
        for (int k = tid; k < KH; k += BLOCK) {
            const int kg = kbase + k;

            float pr0 = pos_raw[2*kg], pr1 = pos_raw[2*kg+1];
            float pos0 = ms / (1.0f + __expf(-pr0));
            float pos1 = ms / (1.0f + __expf(-pr1));

            float cr = conc_raw[kg];
            float conc = fmaxf(cr, 0.0f) + __logf(1.0f + __expf(-fabsf(cr)));

            float s0 = __expf(scale_raw[2*kg]);
            float s1 = __expf(scale_raw[2*kg+1]);
            float d0 = 1.0f / (s0*s0 + EPS);
            float d1 = 1.0f / (s1*s1 + EPS);

            float rot = rot_raw[kg];
            float c = __cosf(rot), s = __sinf(rot);

            float m00 = c*c*d0 + s*s*d1;
            float m01 = c*s*(d0 - d1);
            float m11 = s*s*d0 + c*c*d1;

            float det    = d0 * d1;
            float invdet = 1.0f / det;
            float cc = __log2f(conc) + LOG2_SQRT_2PI - 0.5f * __log2f(det);

            const int q = k >> 2, e = k & 3;
            sG[q][0][e] = m00 * invdet;
            sG[q][1][e] = m01 * invdet;
            sG[q][2][e] = m11 * invdet;
            sG[q][3][e] = cc;
            sG[q][4][e] = pos0;
            sG[q][5][e] = pos1;
        }
        __syncthreads();

        // ---- phase 2: walk this wave-half's chunk ----
        const int g0 = chunk * NG;
        #pragma unroll 4
        for (int gq = 0; gq < NG; ++gq) {
            const int t4 = g0 + gq;
            v4f M00 = *(const v4f*)&sG[t4][0][0];
            v4f M01 = *(const v4f*)&sG[t4][1][0];
            v4f M11 = *(const v4f*)&sG[t4][2][0];
            v4f CC  = *(const v4f*)&sG[t4][3][0];
            v4f P0  = *(const v4f*)&sG[t4][4][0];
            v4f P1  = *(const v4f*)&sG[t4][5][0];

            #pragma unroll
            for (int g = 0; g < 4; ++g) {
                float a_  = fmaf(qu2, M11[g], fmaf(qu1, M01[g], qu0 * M00[g]));
                float cr_ = fmaf(nsu0, P1[g], fmaf(su1, P0[g], wt));
                float ra_ = nr_rsqrt(a_);            // VALU-only (was v_rsq)
                float t_  = cr_ * ra_;
                float ar_ = fmaf(-t_, t_, CC[g]);
                float e_  = __builtin_amdgcn_exp2f(ar_);
                acc = fmaf(ra_, e_, acc);
            }
        }
    }

    // ---- reduction: 32 partials per ray -> one value ----
    acc += __shfl_xor(acc, 32, 64);          // merge the two halves
    if (half == 0) psum[wv][rayl] = acc;
    __syncthreads();

    if (wv == 0 && lane < RPB) {
        float s = 0.0f;
        #pragma unroll
        for (int w = 0; w < NW; ++w) s += psum[w][lane];
        int oray = blockIdx.x * RPB + lane;
        if (oray < R) out[oray] = s;
    }
}

// ---------------------------------------------------------------------------
extern "C" void kernel_launch(void* const* d_in, const int* in_sizes, int n_in,
                              void* d_out, int out_size, void* d_ws, size_t ws_size,
                              hipStream_t stream)
{
    const float* pos_raw   = (const float*)d_in[0];
    const float* conc_raw  = (const float*)d_in[1];
    const float* scale_raw = (const float*)d_in[2];
    const float* rot_raw   = (const float*)d_in[3];
    const float* p_rays    = (const float*)d_in[4];
    const float* u_rays    = (const float*)d_in[5];
    const void*  map_size  = d_in[6];

    const int K = in_sizes[1];          // conc_raw is (K,)
    const int R = out_size;             // output is (R,)

    float* out = (float*)d_out;

    dim3 grid((R + RPB - 1) / RPB);     // 256 blocks for R=8192
    fused_splat<<<grid, BLOCK, 0, stream>>>(pos_raw, conc_raw, scale_raw,
                                            rot_raw, map_size,
                                            p_rays, u_rays, out, K, R);
}